// Round 9
// baseline (747.226 us; speedup 1.0000x reference)
//
#include <hip/hip_runtime.h>
#include <hip/hip_bf16.h>

// VQ-MoE R15: tail attack. vq_mfma = R14 verbatim (192us, passed; k-loop
// plateau confirmed across R8/R9/R10/R14 — 4 different schedules, same dur).
// NEW: rescue is expert-batched. Worklists partitioned by expert (4 counters);
// each rescue block processes 8 same-expert tokens per codebook pass: z rows
// staged in LDS (8KB, broadcast reads), codebook scanned ONCE per batch ->
// L2 traffic per flagged token drops 8x (was ~2MB/token for e=3; est.
// ~120us L2-bound -> ~30us compute-bound). Numerics identical: double dot,
// (zs+csum)-2dot float order, +/-1ulp zsum 3-variant vote, strict-< ties.

#define EPS_GAP 2e-3f
#define NTOK 65536

typedef __attribute__((ext_vector_type(8))) short bf16x8;
typedef __attribute__((ext_vector_type(4))) float f32x4;

__device__ inline unsigned short f2bf(float f) {
  __hip_bfloat16 h = __float2bfloat16(f);
  unsigned short u;
  __builtin_memcpy(&u, &h, 2);
  return u;
}
__device__ inline float bf2f(unsigned short u) {
  return __uint_as_float(((unsigned)u) << 16);
}

__device__ inline void gll16(const unsigned short* g, unsigned short* l) {
  __builtin_amdgcn_global_load_lds(
      (const __attribute__((address_space(1))) unsigned int*)g,
      (__attribute__((address_space(3))) unsigned int*)l, 16, 0, 0);
}

// ---------------- csum + codebook split (+ zero 4 worklist counters) ----------------
__global__ __launch_bounds__(256) void csum_split_kernel(
    const float* __restrict__ cb0, const float* __restrict__ cb1,
    const float* __restrict__ cb2, const float* __restrict__ cb3,
    float* __restrict__ csums, double* __restrict__ csums64,
    unsigned short* __restrict__ cb_hi, unsigned short* __restrict__ cb_lo,
    int* __restrict__ wl_cnt) {
  if (blockIdx.x == 0 && threadIdx.x < 4) wl_cnt[threadIdx.x] = 0;  // stream-ordered init
  int row = blockIdx.x * 4 + (threadIdx.x >> 6);
  int lane = threadIdx.x & 63;
  const float* src; int r;
  if (row < 256)       { src = cb0; r = row; }
  else if (row < 768)  { src = cb1; r = row - 256; }
  else if (row < 1792) { src = cb2; r = row - 768; }
  else                 { src = cb3; r = row - 1792; }
  float4 v = ((const float4*)(src + r * 256))[lane];
  unsigned short h0 = f2bf(v.x), h1 = f2bf(v.y), h2 = f2bf(v.z), h3 = f2bf(v.w);
  unsigned short l0 = f2bf(v.x - bf2f(h0)), l1 = f2bf(v.y - bf2f(h1));
  unsigned short l2 = f2bf(v.z - bf2f(h2)), l3 = f2bf(v.w - bf2f(h3));
  *(ushort4*)(cb_hi + (size_t)row * 256 + lane * 4) = make_ushort4(h0, h1, h2, h3);
  *(ushort4*)(cb_lo + (size_t)row * 256 + lane * 4) = make_ushort4(l0, l1, l2, l3);
  double s = (double)v.x*v.x + (double)v.y*v.y + (double)v.z*v.z + (double)v.w*v.w;
  #pragma unroll
  for (int off = 32; off >= 1; off >>= 1) s += __shfl_down(s, off, 64);
  if (lane == 0) { csums[row] = (float)s; csums64[row] = s; }
}

// ---------------- ze split (bf16 hi/lo) + zsq partials, fused ----------------
__global__ __launch_bounds__(256) void ze_split_kernel(
    const float* __restrict__ z, unsigned short* __restrict__ ze_hi,
    unsigned short* __restrict__ ze_lo, double* __restrict__ parts) {
  const float4* p = (const float4*)z;
  uint2* hi = (uint2*)ze_hi;
  uint2* lo = (uint2*)ze_lo;
  const int n4 = 4194304;
  double s = 0.0;
  for (int i = blockIdx.x * 256 + threadIdx.x; i < n4; i += 256 * 1024) {
    float4 v = p[i];
    unsigned hxy, hzw, lxy, lzw;
    asm("v_cvt_pk_bf16_f32 %0, %1, %2" : "=v"(hxy) : "v"(v.x), "v"(v.y));
    asm("v_cvt_pk_bf16_f32 %0, %1, %2" : "=v"(hzw) : "v"(v.z), "v"(v.w));
    float lx = v.x - __uint_as_float(hxy << 16);
    float ly = v.y - __uint_as_float(hxy & 0xffff0000u);
    float lz = v.z - __uint_as_float(hzw << 16);
    float lw = v.w - __uint_as_float(hzw & 0xffff0000u);
    asm("v_cvt_pk_bf16_f32 %0, %1, %2" : "=v"(lxy) : "v"(lx), "v"(ly));
    asm("v_cvt_pk_bf16_f32 %0, %1, %2" : "=v"(lzw) : "v"(lz), "v"(lw));
    hi[i] = make_uint2(hxy, hzw);
    lo[i] = make_uint2(lxy, lzw);
    s += (double)v.x*(double)v.x + (double)v.y*(double)v.y
       + (double)v.z*(double)v.z + (double)v.w*(double)v.w;
  }
  #pragma unroll
  for (int off = 32; off >= 1; off >>= 1) s += __shfl_down(s, off, 64);
  __shared__ double sh[4];
  if ((threadIdx.x & 63) == 0) sh[threadIdx.x >> 6] = s;
  __syncthreads();
  if (threadIdx.x == 0) parts[blockIdx.x] = sh[0] + sh[1] + sh[2] + sh[3];
}

// ---------------- main: MFMA distances + argmin(+2nd) partials (R14 verbatim) ----------------
__global__ __launch_bounds__(512, 4) void vq_mfma(
    const unsigned short* __restrict__ ze_hi, const unsigned short* __restrict__ ze_lo,
    const int* __restrict__ expert_idx,
    const unsigned short* __restrict__ cb_hi, const unsigned short* __restrict__ cb_lo,
    const float* __restrict__ csums,
    float* __restrict__ D1, int* __restrict__ K1, float* __restrict__ D2) {
  const int b  = blockIdx.y;
  const int e  = expert_idx[b];
  const int hc = blockIdx.z;
  if (hc >= (2 << e)) return;               // inert (uniform exit)
  const int cs_off = (e == 0) ? 0 : (e == 1) ? 256 : (e == 2) ? 768 : 1792;
  const int krow0  = cs_off + hc * 128;
  const int t0     = b * 1024 + blockIdx.x * 128;

  __shared__ unsigned short smem[2 * 2 * 128 * 32];   // B dbuf, 32 KB
  __shared__ float sh_cs[128];

  const int tid = threadIdx.x;
  if (tid < 128) sh_cs[tid] = csums[krow0 + tid];

  const int w = tid >> 6, l = tid & 63;
  const int h = w >> 1, q = w & 1;          // 4 token groups x 2 code halves
  const int m16 = l & 15, g = l >> 4;

  const int srow   = w * 16 + (l >> 2);
  const int schunk = (l & 3) ^ ((srow >> 1) & 3);
  const size_t bsrc = (size_t)(krow0 + srow) * 256 + (size_t)schunk * 8;
  const int wslot = w * 512;

  const size_t a0 = (size_t)(t0 + h * 32 + m16) * 256 + (size_t)g * 8;  // i=0
  const size_t a1 = a0 + 16 * 256;                                      // i=1

  f32x4 acc[2][4];
  #pragma unroll
  for (int i = 0; i < 2; ++i)
    #pragma unroll
    for (int j = 0; j < 4; ++j) acc[i][j] = (f32x4){0.f, 0.f, 0.f, 0.f};

  bf16x8 pAh0, pAl0, pAh1, pAl1;
  bf16x8 qAh0, qAl0, qAh1, qAl1;

  pAh0 = *(const bf16x8*)(ze_hi + a0);
  pAl0 = *(const bf16x8*)(ze_lo + a0);
  pAh1 = *(const bf16x8*)(ze_hi + a1);
  pAl1 = *(const bf16x8*)(ze_lo + a1);
  gll16(cb_hi + bsrc, smem + wslot);
  gll16(cb_lo + bsrc, smem + 4096 + wslot);

#define VQ_STEP(KP, AH0, AL0, AH1, AL1, NH0, NL0, NH1, NL1)             \
  {                                                                     \
    unsigned short* buf_ = smem + ((KP) & 1) * 8192;                    \
    if ((KP) < 7) {                                                     \
      const int kcn_ = ((KP) + 1) * 32;                                 \
      unsigned short* nb_ = smem + (((KP) + 1) & 1) * 8192;             \
      gll16(cb_hi + bsrc + kcn_, nb_ + wslot);                          \
      gll16(cb_lo + bsrc + kcn_, nb_ + 4096 + wslot);                   \
      NH0 = *(const bf16x8*)(ze_hi + a0 + kcn_);                        \
      NL0 = *(const bf16x8*)(ze_lo + a0 + kcn_);                        \
      NH1 = *(const bf16x8*)(ze_hi + a1 + kcn_);                        \
      NL1 = *(const bf16x8*)(ze_lo + a1 + kcn_);                        \
      __builtin_amdgcn_sched_barrier(0);                                \
      asm volatile("s_waitcnt vmcnt(6)" ::: "memory");                  \
    } else {                                                            \
      asm volatile("s_waitcnt vmcnt(0)" ::: "memory");                  \
    }                                                                   \
    __builtin_amdgcn_s_barrier();                                       \
    _Pragma("unroll")                                                   \
    for (int j = 0; j < 4; ++j) {                                       \
      int row_ = q * 64 + j * 16 + m16;                                 \
      int n_ = row_ * 32 + ((g ^ ((row_ >> 1) & 3)) << 3);              \
      bf16x8 bh_ = *(bf16x8*)(buf_ + n_);                               \
      bf16x8 bl_ = *(bf16x8*)(buf_ + 4096 + n_);                        \
      acc[0][j] = __builtin_amdgcn_mfma_f32_16x16x32_bf16(bh_, AH0, acc[0][j], 0, 0, 0); \
      acc[0][j] = __builtin_amdgcn_mfma_f32_16x16x32_bf16(bl_, AH0, acc[0][j], 0, 0, 0); \
      acc[0][j] = __builtin_amdgcn_mfma_f32_16x16x32_bf16(bh_, AL0, acc[0][j], 0, 0, 0); \
      acc[1][j] = __builtin_amdgcn_mfma_f32_16x16x32_bf16(bh_, AH1, acc[1][j], 0, 0, 0); \
      acc[1][j] = __builtin_amdgcn_mfma_f32_16x16x32_bf16(bl_, AH1, acc[1][j], 0, 0, 0); \
      acc[1][j] = __builtin_amdgcn_mfma_f32_16x16x32_bf16(bh_, AL1, acc[1][j], 0, 0, 0); \
    }                                                                   \
    __builtin_amdgcn_sched_barrier(0);                                  \
    __builtin_amdgcn_s_barrier();                                       \
  }

  VQ_STEP(0, pAh0, pAl0, pAh1, pAl1, qAh0, qAl0, qAh1, qAl1)
  VQ_STEP(1, qAh0, qAl0, qAh1, qAl1, pAh0, pAl0, pAh1, pAl1)
  VQ_STEP(2, pAh0, pAl0, pAh1, pAl1, qAh0, qAl0, qAh1, qAl1)
  VQ_STEP(3, qAh0, qAl0, qAh1, qAl1, pAh0, pAl0, pAh1, pAl1)
  VQ_STEP(4, pAh0, pAl0, pAh1, pAl1, qAh0, qAl0, qAh1, qAl1)
  VQ_STEP(5, qAh0, qAl0, qAh1, qAl1, pAh0, pAl0, pAh1, pAl1)
  VQ_STEP(6, pAh0, pAl0, pAh1, pAl1, qAh0, qAl0, qAh1, qAl1)
  VQ_STEP(7, qAh0, qAl0, qAh1, qAl1, pAh0, pAl0, pAh1, pAl1)
#undef VQ_STEP

  __syncthreads();
  float* mD = (float*)smem;
  int*   mK = (int*)(smem + 512);
  float* mS = (float*)(smem + 1024);

  float cst[16];
  #pragma unroll
  for (int j = 0; j < 4; ++j)
    #pragma unroll
    for (int r = 0; r < 4; ++r)
      cst[j * 4 + r] = sh_cs[q * 64 + j * 16 + g * 4 + r];

  #pragma unroll
  for (int i = 0; i < 2; ++i) {
    float bv = 3.4e38f, sv = 3.4e38f; int bk = 0;
    #pragma unroll
    for (int j = 0; j < 4; ++j) {
      #pragma unroll
      for (int r = 0; r < 4; ++r) {
        float d = fmaf(-2.0f, acc[i][j][r], cst[j * 4 + r]);
        int   c = q * 64 + j * 16 + g * 4 + r;
        if (d < bv) { sv = bv; bv = d; bk = c; }
        else        { sv = fminf(sv, d); }
      }
    }
    #pragma unroll
    for (int off = 16; off <= 32; off <<= 1) {
      float ov = __shfl_xor(bv, off);
      int   ok = __shfl_xor(bk, off);
      float os = __shfl_xor(sv, off);
      float nb; int nk;
      if (ov < bv || (ov == bv && ok < bk)) { nb = ov; nk = ok; }
      else                                  { nb = bv; nk = bk; }
      sv = fminf(fmaxf(bv, ov), fminf(sv, os));
      bv = nb; bk = nk;
    }
    if (g == 0) {
      int tloc = h * 32 + i * 16 + m16;
      mD[tloc * 2 + q] = bv;
      mK[tloc * 2 + q] = bk;
      mS[tloc * 2 + q] = sv;
    }
  }
  __syncthreads();
  if (tid < 128) {
    float B = 3.4e38f, S = 3.4e38f; int Kb = 0;
    #pragma unroll
    for (int c = 0; c < 2; ++c) {
      float d1v = mD[tid * 2 + c];
      int   k1v = mK[tid * 2 + c];
      float d2v = mS[tid * 2 + c];
      S = fminf(fmaxf(B, d1v), fminf(S, d2v));
      if (d1v < B) { B = d1v; Kb = k1v; }
    }
    int tg = t0 + tid;
    D1[hc * NTOK + tg] = B;
    K1[hc * NTOK + tg] = hc * 128 + Kb;
    D2[hc * NTOK + tg] = S;
  }
}

// ---------------- combine + zq gather fused (per-expert worklists) ----------------
__global__ __launch_bounds__(256) void combine_kernel(
    const int* __restrict__ expert_idx,
    const float* __restrict__ D1, const int* __restrict__ K1,
    const float* __restrict__ D2,
    const float* __restrict__ cb0, const float* __restrict__ cb1,
    const float* __restrict__ cb2, const float* __restrict__ cb3,
    float* __restrict__ idx_out,
    int* __restrict__ wl, int* __restrict__ wl_cnt,
    double* __restrict__ parts, float* __restrict__ zq_out) {
  __shared__ int sh_idx[256];
  __shared__ double shp[4];
  const int bid = blockIdx.x;
  const int t = bid * 256 + threadIdx.x;
  const int e = expert_idx[bid >> 2];        // uniform per block (256 | 1024)
  const int nch = 2 << e;
  float B = 3.4e38f, S = 3.4e38f; int Kb = 0;
  for (int c = 0; c < nch; ++c) {
    float d1 = D1[c * NTOK + t];
    int   k1 = K1[c * NTOK + t];
    float d2 = D2[c * NTOK + t];
    S = fminf(fmaxf(B, d1), fminf(S, d2));
    if (d1 < B) { B = d1; Kb = k1; }
  }
  idx_out[t] = (float)Kb;
  sh_idx[threadIdx.x] = Kb;
  if (S - B < EPS_GAP) {                     // fused compact, per-expert list
    int p = atomicAdd(wl_cnt + e, 1);
    wl[e * NTOK + p] = t;
  }
  double s = (double)B;
  #pragma unroll
  for (int off = 32; off >= 1; off >>= 1) s += __shfl_down(s, off, 64);
  if ((threadIdx.x & 63) == 0) shp[threadIdx.x >> 6] = s;
  __syncthreads();
  if (threadIdx.x == 0) parts[bid] = shp[0] + shp[1] + shp[2] + shp[3];

  const float* cb = (e == 0) ? cb0 : (e == 1) ? cb1 : (e == 2) ? cb2 : cb3;
  const int wid = threadIdx.x >> 6, lane = threadIdx.x & 63;
  for (int it = 0; it < 64; ++it) {
    int tl = it * 4 + wid;
    int row = sh_idx[tl];
    ((float4*)(zq_out + (size_t)(bid * 256 + tl) * 256))[lane] =
        ((const float4*)(cb + (size_t)row * 256))[lane];
  }
}

// ---------------- rescue v2: expert-batched fp32-emulated re-rank ----------------
// 8 same-expert tokens share ONE codebook scan (8x less L2 traffic/token).
__global__ __launch_bounds__(256) void rescue_kernel(
    const float* __restrict__ z_e,
    const float* __restrict__ cb0, const float* __restrict__ cb1,
    const float* __restrict__ cb2, const float* __restrict__ cb3,
    const double* __restrict__ csums64,
    const int* __restrict__ wl, const int* __restrict__ wl_cnt,
    float* __restrict__ zq_out, float* __restrict__ idx_out) {
  __shared__ float  szrow[8 * 256];
  __shared__ double szs[8];
  __shared__ int    stok[8];
  __shared__ float  sdv[3][256];
  __shared__ int    skv[3][256];
  __shared__ int    s_kc;
  const int tid = threadIdx.x;

  for (int e = 0; e < 4; ++e) {
    const int n_e = wl_cnt[e];
    if (n_e == 0) continue;
    const int K = 256 << e;
    const float* cb = (e == 0) ? cb0 : (e == 1) ? cb1 : (e == 2) ? cb2 : cb3;
    const int off = (e == 0) ? 0 : (e == 1) ? 256 : (e == 2) ? 768 : 1792;
    const double* cs64 = csums64 + off;
    const int nb = (n_e + 7) >> 3;

    for (int bi = blockIdx.x; bi < nb; bi += gridDim.x) {
      const int m = min(8, n_e - bi * 8);
      __syncthreads();                      // previous batch fully done
      if (tid < 8) stok[tid] = (tid < m) ? wl[e * NTOK + bi * 8 + tid] : wl[e * NTOK + bi * 8];
      __syncthreads();
      #pragma unroll
      for (int r = 0; r < 8; ++r)
        szrow[r * 256 + tid] = z_e[(size_t)stok[r] * 256 + tid];
      __syncthreads();
      if (tid < 8) {                        // double zsum per token (exact)
        double s = 0.0;
        for (int i = 0; i < 256; ++i) {
          double v = (double)szrow[tid * 256 + i];
          s += v * v;
        }
        szs[tid] = s;
      }
      __syncthreads();
      unsigned zu[8];
      #pragma unroll
      for (int r = 0; r < 8; ++r) zu[r] = __float_as_uint((float)szs[r]);

      float bd[3][8]; int bk[3][8];
      #pragma unroll
      for (int v = 0; v < 3; ++v)
        #pragma unroll
        for (int r = 0; r < 8; ++r) { bd[v][r] = 3.4e38f; bk[v][r] = 1 << 30; }

      const float4* z4 = (const float4*)szrow;
      for (int k = tid; k < K; k += 256) {
        const float4* c4 = (const float4*)(cb + (size_t)k * 256);
        double acc[8];
        #pragma unroll
        for (int r = 0; r < 8; ++r) acc[r] = 0.0;
        for (int qq = 0; qq < 64; qq += 2) {
          float4 cv0 = c4[qq], cv1 = c4[qq + 1];
          #pragma unroll
          for (int r = 0; r < 8; ++r) {
            float4 zv0 = z4[r * 64 + qq];      // broadcast (uniform addr)
            float4 zv1 = z4[r * 64 + qq + 1];
            acc[r] += (double)zv0.x*cv0.x + (double)zv0.y*cv0.y
                    + (double)zv0.z*cv0.z + (double)zv0.w*cv0.w
                    + (double)zv1.x*cv1.x + (double)zv1.y*cv1.y
                    + (double)zv1.z*cv1.z + (double)zv1.w*cv1.w;
          }
        }
        const float c32 = (float)cs64[k];
        #pragma unroll
        for (int r = 0; r < 8; ++r) {
          const float m2d = (float)(2.0 * acc[r]);
          #pragma unroll
          for (int v = 0; v < 3; ++v) {
            float zsv = __uint_as_float(zu[r] + (unsigned)(v - 1));
            float T1  = zsv + c32;             // numpy order: (zsum+csum) - 2dot
            float d32 = T1 - m2d;
            if (d32 < bd[v][r]) { bd[v][r] = d32; bk[v][r] = k; }
          }
        }
      }

      for (int r = 0; r < m; ++r) {
        #pragma unroll
        for (int v = 0; v < 3; ++v) { sdv[v][tid] = bd[v][r]; skv[v][tid] = bk[v][r]; }
        __syncthreads();
        for (int s = 128; s >= 1; s >>= 1) {
          if (tid < s) {
            #pragma unroll
            for (int v = 0; v < 3; ++v) {
              float od = sdv[v][tid + s]; int ok = skv[v][tid + s];
              if (od < sdv[v][tid] || (od == sdv[v][tid] && ok < skv[v][tid])) {
                sdv[v][tid] = od; skv[v][tid] = ok;
              }
            }
          }
          __syncthreads();
        }
        const int t = stok[r];
        if (tid == 0) {
          int k0 = skv[0][0], k1 = skv[1][0], k2 = skv[2][0];
          int kc = (k0 == k2) ? k0 : k1;     // majority vote over zsum ulp variants
          s_kc = kc;
          idx_out[t] = (float)kc;
        }
        __syncthreads();
        const int kc = s_kc;
        if (tid < 64)
          ((float4*)(zq_out + (size_t)t * 256))[tid] =
              ((const float4*)(cb + (size_t)kc * 256))[tid];
        __syncthreads();
      }
    }
  }
}

// ---------------- finalize: loss = 1.25*(S_comb + S_zsq)/2^32 ----------------
__global__ __launch_bounds__(256) void finalize_kernel(
    const double* __restrict__ parts_comb, const double* __restrict__ parts_zsq,
    float* __restrict__ loss_out) {
  const int tid = threadIdx.x;
  double s = parts_comb[tid] + parts_zsq[tid] + parts_zsq[tid + 256]
           + parts_zsq[tid + 512] + parts_zsq[tid + 768];
  #pragma unroll
  for (int off = 32; off >= 1; off >>= 1) s += __shfl_down(s, off, 64);
  __shared__ double sh[4];
  if ((tid & 63) == 0) sh[tid >> 6] = s;
  __syncthreads();
  if (tid == 0)
    loss_out[0] = (float)((sh[0] + sh[1] + sh[2] + sh[3]) * (1.25 / 4294967296.0));
}

extern "C" void kernel_launch(void* const* d_in, const int* in_sizes, int n_in,
                              void* d_out, int out_size, void* d_ws, size_t ws_size,
                              hipStream_t stream) {
  const float* z_e  = (const float*)d_in[0];
  const int*   eidx = (const int*)d_in[1];
  const float* cb0  = (const float*)d_in[2];
  const float* cb1  = (const float*)d_in[3];
  const float* cb2  = (const float*)d_in[4];
  const float* cb3  = (const float*)d_in[5];

  float* zq    = (float*)d_out;                       // 64*1024*256
  float* idxf  = (float*)d_out + 16777216;            // 64*1024 as floats
  float* lossf = (float*)d_out + 16777216 + 65536;    // 1

  // ze hi/lo scratch aliases the zq output region (64 MB, fully rewritten
  // later by combine-gather + rescue; all uses stream-ordered).
  unsigned short* ze_hi = (unsigned short*)d_out;           // 32 MB
  unsigned short* ze_lo = ze_hi + 16777216;                 // 32 MB

  char* wsp = (char*)d_ws;
  double*         parts_comb = (double*)wsp;           wsp += 256 * 8;
  double*         parts_zsq  = (double*)wsp;           wsp += 1024 * 8;
  double*         csums64    = (double*)wsp;           wsp += 3840 * 8;
  float*          csums      = (float*)wsp;            wsp += 3840 * 4;
  int*            wl_cnt     = (int*)wsp;              wsp += 16;
  int*            wl         = (int*)wsp;              wsp += NTOK * 16;  // 4 expert lists
  unsigned short* cb_hi      = (unsigned short*)wsp;   wsp += 3840 * 256 * 2;
  unsigned short* cb_lo      = (unsigned short*)wsp;   wsp += 3840 * 256 * 2;
  float*          D1         = (float*)wsp;            wsp += 16 * NTOK * 4;
  int*            K1         = (int*)wsp;              wsp += 16 * NTOK * 4;
  float*          D2         = (float*)wsp;            wsp += 16 * NTOK * 4;

  csum_split_kernel<<<960, 256, 0, stream>>>(cb0, cb1, cb2, cb3,
                                             csums, csums64, cb_hi, cb_lo, wl_cnt);
  ze_split_kernel<<<1024, 256, 0, stream>>>(z_e, ze_hi, ze_lo, parts_zsq);
  dim3 grid(8, 64, 16);
  vq_mfma<<<grid, 512, 0, stream>>>(ze_hi, ze_lo, eidx, cb_hi, cb_lo, csums, D1, K1, D2);
  combine_kernel<<<256, 256, 0, stream>>>(eidx, D1, K1, D2, cb0, cb1, cb2, cb3,
                                          idxf, wl, wl_cnt, parts_comb, zq);
  rescue_kernel<<<1024, 256, 0, stream>>>(z_e, cb0, cb1, cb2, cb3,
                                          csums64, wl, wl_cnt, zq, idxf);
  finalize_kernel<<<1, 256, 0, stream>>>(parts_comb, parts_zsq, lossf);
}

// Round 10
// 434.692 us; speedup vs baseline: 1.7190x; 1.7190x over previous
//
#include <hip/hip_runtime.h>
#include <hip/hip_bf16.h>

// VQ-MoE R16: rescue = batch (8 tokens) x split-K (256-code slices) with
// packed-u64 atomicMin merge.
//  R15 lesson: 8-token batching cut codebook traffic 8x (FETCH 16MB) but
//  collapsed parallelism to ~12 blocks (0.6% occupancy) -> 422us. R16 keeps
//  the batch but makes (batch, slice) the block-parallel work item
//  (~nb*K/256 blocks), merging per-slice argmins via atomicMin on sortable
//  (dist,k) u64 -- exact lexicographic min == old strict-< + min-k ties.
//  vq_mfma = R14 verbatim (192us plateau, proven).

#define EPS_GAP 2e-3f
#define NTOK 65536

typedef __attribute__((ext_vector_type(8))) short bf16x8;
typedef __attribute__((ext_vector_type(4))) float f32x4;

__device__ inline unsigned short f2bf(float f) {
  __hip_bfloat16 h = __float2bfloat16(f);
  unsigned short u;
  __builtin_memcpy(&u, &h, 2);
  return u;
}
__device__ inline float bf2f(unsigned short u) {
  return __uint_as_float(((unsigned)u) << 16);
}

__device__ inline void gll16(const unsigned short* g, unsigned short* l) {
  __builtin_amdgcn_global_load_lds(
      (const __attribute__((address_space(1))) unsigned int*)g,
      (__attribute__((address_space(3))) unsigned int*)l, 16, 0, 0);
}

__device__ inline unsigned fenc(float f) {        // monotone sortable encoding
  unsigned u = __float_as_uint(f);
  return (u & 0x80000000u) ? ~u : (u | 0x80000000u);
}
__device__ inline unsigned long long ull_shfl_down(unsigned long long x, int off) {
  unsigned lo = (unsigned)x, hi = (unsigned)(x >> 32);
  lo = __shfl_down(lo, off, 64);
  hi = __shfl_down(hi, off, 64);
  return ((unsigned long long)hi << 32) | lo;
}

// ---------------- csum + codebook split (+ zero 4 worklist counters) ----------------
__global__ __launch_bounds__(256) void csum_split_kernel(
    const float* __restrict__ cb0, const float* __restrict__ cb1,
    const float* __restrict__ cb2, const float* __restrict__ cb3,
    float* __restrict__ csums, double* __restrict__ csums64,
    unsigned short* __restrict__ cb_hi, unsigned short* __restrict__ cb_lo,
    int* __restrict__ wl_cnt) {
  if (blockIdx.x == 0 && threadIdx.x < 4) wl_cnt[threadIdx.x] = 0;  // stream-ordered init
  int row = blockIdx.x * 4 + (threadIdx.x >> 6);
  int lane = threadIdx.x & 63;
  const float* src; int r;
  if (row < 256)       { src = cb0; r = row; }
  else if (row < 768)  { src = cb1; r = row - 256; }
  else if (row < 1792) { src = cb2; r = row - 768; }
  else                 { src = cb3; r = row - 1792; }
  float4 v = ((const float4*)(src + r * 256))[lane];
  unsigned short h0 = f2bf(v.x), h1 = f2bf(v.y), h2 = f2bf(v.z), h3 = f2bf(v.w);
  unsigned short l0 = f2bf(v.x - bf2f(h0)), l1 = f2bf(v.y - bf2f(h1));
  unsigned short l2 = f2bf(v.z - bf2f(h2)), l3 = f2bf(v.w - bf2f(h3));
  *(ushort4*)(cb_hi + (size_t)row * 256 + lane * 4) = make_ushort4(h0, h1, h2, h3);
  *(ushort4*)(cb_lo + (size_t)row * 256 + lane * 4) = make_ushort4(l0, l1, l2, l3);
  double s = (double)v.x*v.x + (double)v.y*v.y + (double)v.z*v.z + (double)v.w*v.w;
  #pragma unroll
  for (int off = 32; off >= 1; off >>= 1) s += __shfl_down(s, off, 64);
  if (lane == 0) { csums[row] = (float)s; csums64[row] = s; }
}

// ---------------- ze split (bf16 hi/lo) + zsq partials, fused ----------------
__global__ __launch_bounds__(256) void ze_split_kernel(
    const float* __restrict__ z, unsigned short* __restrict__ ze_hi,
    unsigned short* __restrict__ ze_lo, double* __restrict__ parts) {
  const float4* p = (const float4*)z;
  uint2* hi = (uint2*)ze_hi;
  uint2* lo = (uint2*)ze_lo;
  const int n4 = 4194304;
  double s = 0.0;
  for (int i = blockIdx.x * 256 + threadIdx.x; i < n4; i += 256 * 1024) {
    float4 v = p[i];
    unsigned hxy, hzw, lxy, lzw;
    asm("v_cvt_pk_bf16_f32 %0, %1, %2" : "=v"(hxy) : "v"(v.x), "v"(v.y));
    asm("v_cvt_pk_bf16_f32 %0, %1, %2" : "=v"(hzw) : "v"(v.z), "v"(v.w));
    float lx = v.x - __uint_as_float(hxy << 16);
    float ly = v.y - __uint_as_float(hxy & 0xffff0000u);
    float lz = v.z - __uint_as_float(hzw << 16);
    float lw = v.w - __uint_as_float(hzw & 0xffff0000u);
    asm("v_cvt_pk_bf16_f32 %0, %1, %2" : "=v"(lxy) : "v"(lx), "v"(ly));
    asm("v_cvt_pk_bf16_f32 %0, %1, %2" : "=v"(lzw) : "v"(lz), "v"(lw));
    hi[i] = make_uint2(hxy, hzw);
    lo[i] = make_uint2(lxy, lzw);
    s += (double)v.x*(double)v.x + (double)v.y*(double)v.y
       + (double)v.z*(double)v.z + (double)v.w*(double)v.w;
  }
  #pragma unroll
  for (int off = 32; off >= 1; off >>= 1) s += __shfl_down(s, off, 64);
  __shared__ double sh[4];
  if ((threadIdx.x & 63) == 0) sh[threadIdx.x >> 6] = s;
  __syncthreads();
  if (threadIdx.x == 0) parts[blockIdx.x] = sh[0] + sh[1] + sh[2] + sh[3];
}

// ---------------- main: MFMA distances + argmin(+2nd) partials (R14 verbatim) ----------------
__global__ __launch_bounds__(512, 4) void vq_mfma(
    const unsigned short* __restrict__ ze_hi, const unsigned short* __restrict__ ze_lo,
    const int* __restrict__ expert_idx,
    const unsigned short* __restrict__ cb_hi, const unsigned short* __restrict__ cb_lo,
    const float* __restrict__ csums,
    float* __restrict__ D1, int* __restrict__ K1, float* __restrict__ D2) {
  const int b  = blockIdx.y;
  const int e  = expert_idx[b];
  const int hc = blockIdx.z;
  if (hc >= (2 << e)) return;               // inert (uniform exit)
  const int cs_off = (e == 0) ? 0 : (e == 1) ? 256 : (e == 2) ? 768 : 1792;
  const int krow0  = cs_off + hc * 128;
  const int t0     = b * 1024 + blockIdx.x * 128;

  __shared__ unsigned short smem[2 * 2 * 128 * 32];   // B dbuf, 32 KB
  __shared__ float sh_cs[128];

  const int tid = threadIdx.x;
  if (tid < 128) sh_cs[tid] = csums[krow0 + tid];

  const int w = tid >> 6, l = tid & 63;
  const int h = w >> 1, q = w & 1;          // 4 token groups x 2 code halves
  const int m16 = l & 15, g = l >> 4;

  const int srow   = w * 16 + (l >> 2);
  const int schunk = (l & 3) ^ ((srow >> 1) & 3);
  const size_t bsrc = (size_t)(krow0 + srow) * 256 + (size_t)schunk * 8;
  const int wslot = w * 512;

  const size_t a0 = (size_t)(t0 + h * 32 + m16) * 256 + (size_t)g * 8;  // i=0
  const size_t a1 = a0 + 16 * 256;                                      // i=1

  f32x4 acc[2][4];
  #pragma unroll
  for (int i = 0; i < 2; ++i)
    #pragma unroll
    for (int j = 0; j < 4; ++j) acc[i][j] = (f32x4){0.f, 0.f, 0.f, 0.f};

  bf16x8 pAh0, pAl0, pAh1, pAl1;
  bf16x8 qAh0, qAl0, qAh1, qAl1;

  pAh0 = *(const bf16x8*)(ze_hi + a0);
  pAl0 = *(const bf16x8*)(ze_lo + a0);
  pAh1 = *(const bf16x8*)(ze_hi + a1);
  pAl1 = *(const bf16x8*)(ze_lo + a1);
  gll16(cb_hi + bsrc, smem + wslot);
  gll16(cb_lo + bsrc, smem + 4096 + wslot);

#define VQ_STEP(KP, AH0, AL0, AH1, AL1, NH0, NL0, NH1, NL1)             \
  {                                                                     \
    unsigned short* buf_ = smem + ((KP) & 1) * 8192;                    \
    if ((KP) < 7) {                                                     \
      const int kcn_ = ((KP) + 1) * 32;                                 \
      unsigned short* nb_ = smem + (((KP) + 1) & 1) * 8192;             \
      gll16(cb_hi + bsrc + kcn_, nb_ + wslot);                          \
      gll16(cb_lo + bsrc + kcn_, nb_ + 4096 + wslot);                   \
      NH0 = *(const bf16x8*)(ze_hi + a0 + kcn_);                        \
      NL0 = *(const bf16x8*)(ze_lo + a0 + kcn_);                        \
      NH1 = *(const bf16x8*)(ze_hi + a1 + kcn_);                        \
      NL1 = *(const bf16x8*)(ze_lo + a1 + kcn_);                        \
      __builtin_amdgcn_sched_barrier(0);                                \
      asm volatile("s_waitcnt vmcnt(6)" ::: "memory");                  \
    } else {                                                            \
      asm volatile("s_waitcnt vmcnt(0)" ::: "memory");                  \
    }                                                                   \
    __builtin_amdgcn_s_barrier();                                       \
    _Pragma("unroll")                                                   \
    for (int j = 0; j < 4; ++j) {                                       \
      int row_ = q * 64 + j * 16 + m16;                                 \
      int n_ = row_ * 32 + ((g ^ ((row_ >> 1) & 3)) << 3);              \
      bf16x8 bh_ = *(bf16x8*)(buf_ + n_);                               \
      bf16x8 bl_ = *(bf16x8*)(buf_ + 4096 + n_);                        \
      acc[0][j] = __builtin_amdgcn_mfma_f32_16x16x32_bf16(bh_, AH0, acc[0][j], 0, 0, 0); \
      acc[0][j] = __builtin_amdgcn_mfma_f32_16x16x32_bf16(bl_, AH0, acc[0][j], 0, 0, 0); \
      acc[0][j] = __builtin_amdgcn_mfma_f32_16x16x32_bf16(bh_, AL0, acc[0][j], 0, 0, 0); \
      acc[1][j] = __builtin_amdgcn_mfma_f32_16x16x32_bf16(bh_, AH1, acc[1][j], 0, 0, 0); \
      acc[1][j] = __builtin_amdgcn_mfma_f32_16x16x32_bf16(bl_, AH1, acc[1][j], 0, 0, 0); \
      acc[1][j] = __builtin_amdgcn_mfma_f32_16x16x32_bf16(bh_, AL1, acc[1][j], 0, 0, 0); \
    }                                                                   \
    __builtin_amdgcn_sched_barrier(0);                                  \
    __builtin_amdgcn_s_barrier();                                       \
  }

  VQ_STEP(0, pAh0, pAl0, pAh1, pAl1, qAh0, qAl0, qAh1, qAl1)
  VQ_STEP(1, qAh0, qAl0, qAh1, qAl1, pAh0, pAl0, pAh1, pAl1)
  VQ_STEP(2, pAh0, pAl0, pAh1, pAl1, qAh0, qAl0, qAh1, qAl1)
  VQ_STEP(3, qAh0, qAl0, qAh1, qAl1, pAh0, pAl0, pAh1, pAl1)
  VQ_STEP(4, pAh0, pAl0, pAh1, pAl1, qAh0, qAl0, qAh1, qAl1)
  VQ_STEP(5, qAh0, qAl0, qAh1, qAl1, pAh0, pAl0, pAh1, pAl1)
  VQ_STEP(6, pAh0, pAl0, pAh1, pAl1, qAh0, qAl0, qAh1, qAl1)
  VQ_STEP(7, qAh0, qAl0, qAh1, qAl1, pAh0, pAl0, pAh1, pAl1)
#undef VQ_STEP

  __syncthreads();
  float* mD = (float*)smem;
  int*   mK = (int*)(smem + 512);
  float* mS = (float*)(smem + 1024);

  float cst[16];
  #pragma unroll
  for (int j = 0; j < 4; ++j)
    #pragma unroll
    for (int r = 0; r < 4; ++r)
      cst[j * 4 + r] = sh_cs[q * 64 + j * 16 + g * 4 + r];

  #pragma unroll
  for (int i = 0; i < 2; ++i) {
    float bv = 3.4e38f, sv = 3.4e38f; int bk = 0;
    #pragma unroll
    for (int j = 0; j < 4; ++j) {
      #pragma unroll
      for (int r = 0; r < 4; ++r) {
        float d = fmaf(-2.0f, acc[i][j][r], cst[j * 4 + r]);
        int   c = q * 64 + j * 16 + g * 4 + r;
        if (d < bv) { sv = bv; bv = d; bk = c; }
        else        { sv = fminf(sv, d); }
      }
    }
    #pragma unroll
    for (int off = 16; off <= 32; off <<= 1) {
      float ov = __shfl_xor(bv, off);
      int   ok = __shfl_xor(bk, off);
      float os = __shfl_xor(sv, off);
      float nb; int nk;
      if (ov < bv || (ov == bv && ok < bk)) { nb = ov; nk = ok; }
      else                                  { nb = bv; nk = bk; }
      sv = fminf(fmaxf(bv, ov), fminf(sv, os));
      bv = nb; bk = nk;
    }
    if (g == 0) {
      int tloc = h * 32 + i * 16 + m16;
      mD[tloc * 2 + q] = bv;
      mK[tloc * 2 + q] = bk;
      mS[tloc * 2 + q] = sv;
    }
  }
  __syncthreads();
  if (tid < 128) {
    float B = 3.4e38f, S = 3.4e38f; int Kb = 0;
    #pragma unroll
    for (int c = 0; c < 2; ++c) {
      float d1v = mD[tid * 2 + c];
      int   k1v = mK[tid * 2 + c];
      float d2v = mS[tid * 2 + c];
      S = fminf(fmaxf(B, d1v), fminf(S, d2v));
      if (d1v < B) { B = d1v; Kb = k1v; }
    }
    int tg = t0 + tid;
    D1[hc * NTOK + tg] = B;
    K1[hc * NTOK + tg] = hc * 128 + Kb;
    D2[hc * NTOK + tg] = S;
  }
}

// ---------------- combine + zq gather fused (per-expert worklists + pk init) ----------------
__global__ __launch_bounds__(256) void combine_kernel(
    const int* __restrict__ expert_idx,
    const float* __restrict__ D1, const int* __restrict__ K1,
    const float* __restrict__ D2,
    const float* __restrict__ cb0, const float* __restrict__ cb1,
    const float* __restrict__ cb2, const float* __restrict__ cb3,
    float* __restrict__ idx_out,
    int* __restrict__ wl, int* __restrict__ wl_cnt,
    unsigned long long* __restrict__ pk,
    double* __restrict__ parts, float* __restrict__ zq_out) {
  __shared__ int sh_idx[256];
  __shared__ double shp[4];
  const int bid = blockIdx.x;
  const int t = bid * 256 + threadIdx.x;
  const int e = expert_idx[bid >> 2];        // uniform per block (256 | 1024)
  const int nch = 2 << e;
  float B = 3.4e38f, S = 3.4e38f; int Kb = 0;
  for (int c = 0; c < nch; ++c) {
    float d1 = D1[c * NTOK + t];
    int   k1 = K1[c * NTOK + t];
    float d2 = D2[c * NTOK + t];
    S = fminf(fmaxf(B, d1), fminf(S, d2));
    if (d1 < B) { B = d1; Kb = k1; }
  }
  idx_out[t] = (float)Kb;
  sh_idx[threadIdx.x] = Kb;
  if (S - B < EPS_GAP) {                     // fused compact, per-expert list
    int p = atomicAdd(wl_cnt + e, 1);
    wl[e * NTOK + p] = t;
    pk[t] = ~0ull; pk[NTOK + t] = ~0ull; pk[2 * NTOK + t] = ~0ull;
  }
  double s = (double)B;
  #pragma unroll
  for (int off = 32; off >= 1; off >>= 1) s += __shfl_down(s, off, 64);
  if ((threadIdx.x & 63) == 0) shp[threadIdx.x >> 6] = s;
  __syncthreads();
  if (threadIdx.x == 0) parts[bid] = shp[0] + shp[1] + shp[2] + shp[3];

  const float* cb = (e == 0) ? cb0 : (e == 1) ? cb1 : (e == 2) ? cb2 : cb3;
  const int wid = threadIdx.x >> 6, lane = threadIdx.x & 63;
  for (int it = 0; it < 64; ++it) {
    int tl = it * 4 + wid;
    int row = sh_idx[tl];
    ((float4*)(zq_out + (size_t)(bid * 256 + tl) * 256))[lane] =
        ((const float4*)(cb + (size_t)row * 256))[lane];
  }
}

// ---------------- rescue scan: (8-token batch) x (256-code slice) items ----------------
__global__ __launch_bounds__(256) void rescue_scan_kernel(
    const float* __restrict__ z_e,
    const float* __restrict__ cb0, const float* __restrict__ cb1,
    const float* __restrict__ cb2, const float* __restrict__ cb3,
    const double* __restrict__ csums64,
    const int* __restrict__ wl, const int* __restrict__ wl_cnt,
    unsigned long long* __restrict__ pk) {
  __shared__ float  szrow[8 * 256];
  __shared__ double szs[8];
  __shared__ int    stok[8];
  __shared__ unsigned long long swp[3][4];
  const int tid = threadIdx.x;
  const int wid = tid >> 6, lane = tid & 63;

  for (int e = 0; e < 4; ++e) {
    const int n_e = wl_cnt[e];
    if (n_e == 0) continue;
    const float* cb = (e == 0) ? cb0 : (e == 1) ? cb1 : (e == 2) ? cb2 : cb3;
    const int off = (e == 0) ? 0 : (e == 1) ? 256 : (e == 2) ? 768 : 1792;
    const double* cs64 = csums64 + off;
    const int nb = (n_e + 7) >> 3;
    const int items = nb << e;               // slices of 256 codes each

    for (int item = blockIdx.x; item < items; item += gridDim.x) {
      const int bi = item >> e;
      const int slice = item & ((1 << e) - 1);
      const int m = min(8, n_e - bi * 8);
      __syncthreads();                       // previous item fully done
      if (tid < 8) stok[tid] = (tid < m) ? wl[e * NTOK + bi * 8 + tid]
                                         : wl[e * NTOK + bi * 8];  // pad = dup tok0
      __syncthreads();
      #pragma unroll
      for (int r = 0; r < 8; ++r)
        szrow[r * 256 + tid] = z_e[(size_t)stok[r] * 256 + tid];
      __syncthreads();
      if (tid < 8) {                         // double zsum per token
        double s = 0.0;
        for (int i = 0; i < 256; ++i) {
          double v = (double)szrow[tid * 256 + i];
          s += v * v;
        }
        szs[tid] = s;
      }
      __syncthreads();

      const int k = slice * 256 + tid;       // one code per thread
      const float4* c4 = (const float4*)(cb + (size_t)k * 256);
      const float c32 = (float)cs64[k];
      const float4* z4 = (const float4*)szrow;
      double acc[8];
      #pragma unroll
      for (int r = 0; r < 8; ++r) acc[r] = 0.0;
      for (int qq = 0; qq < 64; qq += 2) {
        float4 cv0 = c4[qq], cv1 = c4[qq + 1];
        #pragma unroll
        for (int r = 0; r < 8; ++r) {
          float4 zv0 = z4[r * 64 + qq];      // broadcast (uniform addr)
          float4 zv1 = z4[r * 64 + qq + 1];
          acc[r] += (double)zv0.x*cv0.x + (double)zv0.y*cv0.y
                  + (double)zv0.z*cv0.z + (double)zv0.w*cv0.w
                  + (double)zv1.x*cv1.x + (double)zv1.y*cv1.y
                  + (double)zv1.z*cv1.z + (double)zv1.w*cv1.w;
        }
      }
      unsigned zu[8];
      #pragma unroll
      for (int r = 0; r < 8; ++r) zu[r] = __float_as_uint((float)szs[r]);

      // per token (dups for r>=m are idempotent re-updates of token 0):
      #pragma unroll
      for (int r = 0; r < 8; ++r) {
        const float m2d = (float)(2.0 * acc[r]);
        #pragma unroll
        for (int v = 0; v < 3; ++v) {
          float zsv = __uint_as_float(zu[r] + (unsigned)(v - 1));
          float T1  = zsv + c32;             // numpy order: (zsum+csum) - 2dot
          float d32 = T1 - m2d;
          unsigned long long p = ((unsigned long long)fenc(d32) << 32) | (unsigned)k;
          #pragma unroll
          for (int o = 32; o >= 1; o >>= 1) {
            unsigned long long q = ull_shfl_down(p, o);
            p = (q < p) ? q : p;
          }
          if (lane == 0) swp[v][wid] = p;
        }
        __syncthreads();
        if (tid == 0) {
          const int tok = stok[r];
          #pragma unroll
          for (int v = 0; v < 3; ++v) {
            unsigned long long mn = swp[v][0];
            if (swp[v][1] < mn) mn = swp[v][1];
            if (swp[v][2] < mn) mn = swp[v][2];
            if (swp[v][3] < mn) mn = swp[v][3];
            atomicMin(pk + (size_t)v * NTOK + tok, mn);
          }
        }
        __syncthreads();
      }
    }
  }
}

// ---------------- rescue finish: vote + idx/zq write, one block per token ----------------
__global__ __launch_bounds__(256) void rescue_finish_kernel(
    const float* __restrict__ cb0, const float* __restrict__ cb1,
    const float* __restrict__ cb2, const float* __restrict__ cb3,
    const int* __restrict__ wl, const int* __restrict__ wl_cnt,
    const unsigned long long* __restrict__ pk,
    float* __restrict__ zq_out, float* __restrict__ idx_out) {
  __shared__ int s_kc;
  for (int e = 0; e < 4; ++e) {
    const int n_e = wl_cnt[e];
    if (n_e == 0) continue;
    const float* cb = (e == 0) ? cb0 : (e == 1) ? cb1 : (e == 2) ? cb2 : cb3;
    for (int i = blockIdx.x; i < n_e; i += gridDim.x) {
      const int t = wl[e * NTOK + i];
      __syncthreads();
      if (threadIdx.x == 0) {
        int k0 = (int)(pk[t] & 0xFFFFFFFFull);
        int k1 = (int)(pk[NTOK + t] & 0xFFFFFFFFull);
        int k2 = (int)(pk[2 * NTOK + t] & 0xFFFFFFFFull);
        int kc = (k0 == k2) ? k0 : k1;       // majority vote over zsum ulp variants
        s_kc = kc;
        idx_out[t] = (float)kc;
      }
      __syncthreads();
      const int kc = s_kc;
      if (threadIdx.x < 64)
        ((float4*)(zq_out + (size_t)t * 256))[threadIdx.x] =
            ((const float4*)(cb + (size_t)kc * 256))[threadIdx.x];
    }
  }
}

// ---------------- finalize: loss = 1.25*(S_comb + S_zsq)/2^32 ----------------
__global__ __launch_bounds__(256) void finalize_kernel(
    const double* __restrict__ parts_comb, const double* __restrict__ parts_zsq,
    float* __restrict__ loss_out) {
  const int tid = threadIdx.x;
  double s = parts_comb[tid] + parts_zsq[tid] + parts_zsq[tid + 256]
           + parts_zsq[tid + 512] + parts_zsq[tid + 768];
  #pragma unroll
  for (int off = 32; off >= 1; off >>= 1) s += __shfl_down(s, off, 64);
  __shared__ double sh[4];
  if ((tid & 63) == 0) sh[tid >> 6] = s;
  __syncthreads();
  if (tid == 0)
    loss_out[0] = (float)((sh[0] + sh[1] + sh[2] + sh[3]) * (1.25 / 4294967296.0));
}

extern "C" void kernel_launch(void* const* d_in, const int* in_sizes, int n_in,
                              void* d_out, int out_size, void* d_ws, size_t ws_size,
                              hipStream_t stream) {
  const float* z_e  = (const float*)d_in[0];
  const int*   eidx = (const int*)d_in[1];
  const float* cb0  = (const float*)d_in[2];
  const float* cb1  = (const float*)d_in[3];
  const float* cb2  = (const float*)d_in[4];
  const float* cb3  = (const float*)d_in[5];

  float* zq    = (float*)d_out;                       // 64*1024*256
  float* idxf  = (float*)d_out + 16777216;            // 64*1024 as floats
  float* lossf = (float*)d_out + 16777216 + 65536;    // 1

  // ze hi/lo scratch aliases the zq output region (64 MB, fully rewritten
  // later by combine-gather + rescue; all uses stream-ordered).
  unsigned short* ze_hi = (unsigned short*)d_out;           // 32 MB
  unsigned short* ze_lo = ze_hi + 16777216;                 // 32 MB

  char* wsp = (char*)d_ws;
  double*             parts_comb = (double*)wsp;             wsp += 256 * 8;
  double*             parts_zsq  = (double*)wsp;             wsp += 1024 * 8;
  double*             csums64    = (double*)wsp;             wsp += 3840 * 8;
  float*              csums      = (float*)wsp;              wsp += 3840 * 4;
  int*                wl_cnt     = (int*)wsp;                wsp += 16;
  int*                wl         = (int*)wsp;                wsp += NTOK * 16;  // 4 expert lists
  unsigned long long* pk         = (unsigned long long*)wsp; wsp += NTOK * 3 * 8;
  unsigned short*     cb_hi      = (unsigned short*)wsp;     wsp += 3840 * 256 * 2;
  unsigned short*     cb_lo      = (unsigned short*)wsp;     wsp += 3840 * 256 * 2;
  float*              D1         = (float*)wsp;              wsp += 16 * NTOK * 4;
  int*                K1         = (int*)wsp;                wsp += 16 * NTOK * 4;
  float*              D2         = (float*)wsp;              wsp += 16 * NTOK * 4;

  csum_split_kernel<<<960, 256, 0, stream>>>(cb0, cb1, cb2, cb3,
                                             csums, csums64, cb_hi, cb_lo, wl_cnt);
  ze_split_kernel<<<1024, 256, 0, stream>>>(z_e, ze_hi, ze_lo, parts_zsq);
  dim3 grid(8, 64, 16);
  vq_mfma<<<grid, 512, 0, stream>>>(ze_hi, ze_lo, eidx, cb_hi, cb_lo, csums, D1, K1, D2);
  combine_kernel<<<256, 256, 0, stream>>>(eidx, D1, K1, D2, cb0, cb1, cb2, cb3,
                                          idxf, wl, wl_cnt, pk, parts_comb, zq);
  rescue_scan_kernel<<<1024, 256, 0, stream>>>(z_e, cb0, cb1, cb2, cb3,
                                               csums64, wl, wl_cnt, pk);
  rescue_finish_kernel<<<512, 256, 0, stream>>>(cb0, cb1, cb2, cb3,
                                                wl, wl_cnt, pk, zq, idxf);
  finalize_kernel<<<1, 256, 0, stream>>>(parts_comb, parts_zsq, lossf);
}